// Round 4
// baseline (2304.933 us; speedup 1.0000x reference)
//
#include <hip/hip_runtime.h>
#include <stdint.h>

// Elman RNN, B=64 T=512 E=H=O=512, fp32 in/out, bf16 MFMA compute.
// Pipeline: cast x -> bf16; transpose W1,W2 -> [N][K] bf16;
//   Phase A: Xc1 = x@W1x + b1            (parallel GEMM, bf16 out, into d_out scratch)
//   Phase B: h_{t+1}=sigmoid(Xc1[t]+h@W1h)  (64 WGs, 1 per batch, W1h in VGPRs)
//   Phase C: out = x@W2x + Hall@W2h + b2 (parallel GEMM K=1024, f32 out)
// d_ws use: 66 MB (xb 32MB | W1T 1MB | W2T 1MB | Hall 32MB). Xc1b lives in
// d_out bytes [0,33.5MB) -- consumed by phase B, then overwritten by phase C.

typedef unsigned short u16;
typedef short s16;
typedef s16 s16x8 __attribute__((ext_vector_type(8)));
typedef u16 u16x8 __attribute__((ext_vector_type(8)));
typedef float f32x4 __attribute__((ext_vector_type(4)));

__device__ __forceinline__ u16 f2b(float f) {  // f32 -> bf16 RNE
  uint32_t x = __float_as_uint(f);
  uint32_t r = x + 0x7FFFu + ((x >> 16) & 1u);
  return (u16)(r >> 16);
}
__device__ __forceinline__ float b2f(u16 u) {
  return __uint_as_float(((uint32_t)u) << 16);
}

typedef const __attribute__((address_space(1))) uint32_t* gp32;
typedef __attribute__((address_space(3))) uint32_t* lp32;
__device__ __forceinline__ void gload_lds16(const void* g, void* l) {
  __builtin_amdgcn_global_load_lds((gp32)g, (lp32)l, 16, 0, 0);
}

// ---------------- cast x (f32 -> bf16), 8 elems/thread ----------------
__global__ __launch_bounds__(256) void cast_x_kernel(const float* __restrict__ x,
                                                     u16* __restrict__ xb, int n) {
  int i = (blockIdx.x * 256 + threadIdx.x) * 8;
  if (i >= n) return;
  const float4* p = (const float4*)(x + i);
  float4 v0 = p[0], v1 = p[1];
  u16x8 o;
  o[0] = f2b(v0.x); o[1] = f2b(v0.y); o[2] = f2b(v0.z); o[3] = f2b(v0.w);
  o[4] = f2b(v1.x); o[5] = f2b(v1.y); o[6] = f2b(v1.z); o[7] = f2b(v1.w);
  *(u16x8*)(xb + i) = o;
}

// -------- W [1024][512] f32 -> WT [512][1024] bf16 (LDS tiled) --------
__global__ __launch_bounds__(256) void transpose_cast_kernel(const float* __restrict__ W,
                                                             u16* __restrict__ WT) {
  __shared__ u16 tile[32][33];
  int tx = threadIdx.x, ty = threadIdx.y;
  int kt = blockIdx.x * 32, nt = blockIdx.y * 32;
#pragma unroll
  for (int i = 0; i < 4; ++i) {
    int k = kt + ty + i * 8;
    tile[ty + i * 8][tx] = f2b(W[k * 512 + nt + tx]);
  }
  __syncthreads();
#pragma unroll
  for (int i = 0; i < 4; ++i) {
    int n = nt + ty + i * 8;
    WT[n * 1024 + kt + tx] = tile[tx][ty + i * 8];
  }
}

// ---------------- GEMM: C[M=32768][512] = A@B^T + bias ----------------
// A rows: k<512 from A1 (ld 512), k>=512 from A2 (ld 512). BT: [512][1024].
// 128x128 tile, BK=64, 4 waves, each wave a 64x64 quadrant (4x4 16x16 frags).
__global__ __launch_bounds__(256) void gemm_kernel(
    const u16* __restrict__ A1, const u16* __restrict__ A2,
    const u16* __restrict__ BT, const float* __restrict__ bias,
    void* __restrict__ Cout, int K2, int outF32) {
  __shared__ u16 As[128 * 64];
  __shared__ u16 Bs[128 * 64];
  int tid = threadIdx.x;
  int lane = tid & 63, w = tid >> 6, wm = w >> 1, wn = w & 1;
  int cg = lane >> 4, cl = lane & 15;
  int m0 = blockIdx.x * 128, n0 = blockIdx.y * 128;
  int KT = (512 + K2) / 64;

  f32x4 z = {0.f, 0.f, 0.f, 0.f};
  f32x4 acc[4][4];
#pragma unroll
  for (int i = 0; i < 4; ++i)
#pragma unroll
    for (int j = 0; j < 4; ++j) acc[i][j] = z;

  int arow = tid >> 3;        // 0..31
  int kc = (tid & 7) * 8;     // 0..56

  for (int kt = 0; kt < KT; ++kt) {
    int kg = kt * 64;
    const u16* Abase;
    int kA;
    if (kg < 512) { Abase = A1; kA = kg; }
    else          { Abase = A2; kA = kg - 512; }
#pragma unroll
    for (int r = 0; r < 4; ++r) {
      const u16* ga = Abase + (size_t)(m0 + r * 32 + arow) * 512 + kA + kc;
      gload_lds16(ga, As + r * 2048 + tid * 8);
      const u16* gb = BT + (size_t)(n0 + r * 32 + arow) * 1024 + kg + kc;
      gload_lds16(gb, Bs + r * 2048 + tid * 8);
    }
    __syncthreads();   // drains vmcnt(0): staged tiles visible
#pragma unroll
    for (int ks = 0; ks < 2; ++ks) {
      s16x8 af[4], bf[4];
#pragma unroll
      for (int i = 0; i < 4; ++i)
        af[i] = *(const s16x8*)(As + (wm * 64 + i * 16 + cl) * 64 + ks * 32 + cg * 8);
#pragma unroll
      for (int j = 0; j < 4; ++j)
        bf[j] = *(const s16x8*)(Bs + (wn * 64 + j * 16 + cl) * 64 + ks * 32 + cg * 8);
#pragma unroll
      for (int i = 0; i < 4; ++i)
#pragma unroll
        for (int j = 0; j < 4; ++j)
          acc[i][j] = __builtin_amdgcn_mfma_f32_16x16x32_bf16(af[i], bf[j], acc[i][j], 0, 0, 0);
    }
    __syncthreads();
  }

  // epilogue: C/D mapping col=lane&15, row=(lane>>4)*4+reg
#pragma unroll
  for (int i = 0; i < 4; ++i) {
#pragma unroll
    for (int j = 0; j < 4; ++j) {
      int col = n0 + wn * 64 + j * 16 + cl;
      float bv = bias[col];
      int row0 = m0 + wm * 64 + i * 16 + cg * 4;
#pragma unroll
      for (int r = 0; r < 4; ++r) {
        float v = acc[i][j][r] + bv;
        size_t off = (size_t)(row0 + r) * 512 + col;
        if (outF32) ((float*)Cout)[off] = v;
        else        ((u16*)Cout)[off] = f2b(v);
      }
    }
  }
}

// ---------------- Phase B: recurrence, one WG (16 waves) per batch ----------------
// W1h held in registers: wave w owns output cols [32w,32w+32) as 2 col-tiles.
// A operand = h broadcast into all 16 MFMA rows (row-mapping agnostic).
__global__ __launch_bounds__(1024, 1) void elman_rec_kernel(
    const u16* __restrict__ W1T, const u16* __restrict__ Xc1b,
    u16* __restrict__ Hall, float* __restrict__ outHidden) {
  __shared__ u16 hbuf[2][512];
  int b = blockIdx.x;
  int tid = threadIdx.x;
  int lane = tid & 63, w = tid >> 6;   // w: 0..15
  int cg = lane >> 4, cl = lane & 15;

  // B fragments: lane -> W1h[k = kb*32 + cg*8 + j][n], n = 32w (+16) + cl
  s16x8 bfrag0[16], bfrag1[16];
  {
    const u16* base0 = W1T + (size_t)(w * 32 + cl) * 1024 + 512;
    const u16* base1 = W1T + (size_t)(w * 32 + 16 + cl) * 1024 + 512;
#pragma unroll
    for (int kb = 0; kb < 16; ++kb) {
      bfrag0[kb] = *(const s16x8*)(base0 + kb * 32 + cg * 8);
      bfrag1[kb] = *(const s16x8*)(base1 + kb * 32 + cg * 8);
    }
  }

  if (tid < 512) {
    hbuf[0][tid] = 0;                                  // h_0 = 0
    Hall[(size_t)b * 512 * 512 + tid] = 0;             // Hall[b][0][:] = 0
  }
  __syncthreads();

  const u16* xcbase = Xc1b + (size_t)b * 512 * 512;
  int col0 = w * 32 + cl, col1 = w * 32 + 16 + cl;
  int cur = 0;
  for (int t = 0; t < 512; ++t) {
    const u16* xr = xcbase + t * 512;
    u16 xu0 = xr[col0], xu1 = xr[col1];                // prefetch early

    s16x8 a[16];
#pragma unroll
    for (int kb = 0; kb < 16; ++kb)
      a[kb] = *(const s16x8*)(&hbuf[cur][kb * 32 + cg * 8]);

    f32x4 a0a = {0.f,0.f,0.f,0.f}, a0b = a0a, a1a = a0a, a1b = a0a;  // 2-way K-split for ILP
#pragma unroll
    for (int kb = 0; kb < 8; ++kb) {
      a0a = __builtin_amdgcn_mfma_f32_16x16x32_bf16(a[kb], bfrag0[kb], a0a, 0, 0, 0);
      a1a = __builtin_amdgcn_mfma_f32_16x16x32_bf16(a[kb], bfrag1[kb], a1a, 0, 0, 0);
      a0b = __builtin_amdgcn_mfma_f32_16x16x32_bf16(a[kb + 8], bfrag0[kb + 8], a0b, 0, 0, 0);
      a1b = __builtin_amdgcn_mfma_f32_16x16x32_bf16(a[kb + 8], bfrag1[kb + 8], a1b, 0, 0, 0);
    }
    float pre0 = b2f(xu0) + a0a[0] + a0b[0];
    float pre1 = b2f(xu1) + a1a[0] + a1b[0];
    float h0 = 1.0f / (1.0f + __expf(-pre0));
    float h1 = 1.0f / (1.0f + __expf(-pre1));
    int nxt = cur ^ 1;
    if (lane < 16) {
      hbuf[nxt][col0] = f2b(h0);
      hbuf[nxt][col1] = f2b(h1);
      if (t < 511) {
        u16* hr = Hall + (size_t)b * 512 * 512 + (size_t)(t + 1) * 512;
        hr[col0] = f2b(h0);
        hr[col1] = f2b(h1);
      } else {
        outHidden[b * 512 + col0] = h0;
        outHidden[b * 512 + col1] = h1;
      }
    }
    __syncthreads();
    cur = nxt;
  }
}

extern "C" void kernel_launch(void* const* d_in, const int* in_sizes, int n_in,
                              void* d_out, int out_size, void* d_ws, size_t ws_size,
                              hipStream_t stream) {
  const float* x  = (const float*)d_in[0];
  const float* W1 = (const float*)d_in[1];
  const float* b1 = (const float*)d_in[2];
  const float* W2 = (const float*)d_in[3];
  const float* b2 = (const float*)d_in[4];
  float* out = (float*)d_out;

  char* ws = (char*)d_ws;
  u16* xb   = (u16*)(ws);                   // 33,554,432 B
  u16* W1T  = (u16*)(ws + 33554432);        //  1,048,576 B
  u16* W2T  = (u16*)(ws + 34603008);        //  1,048,576 B
  u16* Hall = (u16*)(ws + 35651584);        // 33,554,432 B  (total ~66 MB)
  u16* Xc1b = (u16*)d_out;                  // scratch in d_out bytes [0, 33.5MB)
                                            // (outHidden tail at byte 67.1MB untouched;
                                            //  phase C overwrites after Xc1b is dead)

  cast_x_kernel<<<8192, 256, 0, stream>>>(x, xb, 64 * 512 * 512);
  transpose_cast_kernel<<<dim3(32, 16), dim3(32, 8), 0, stream>>>(W1, W1T);
  transpose_cast_kernel<<<dim3(32, 16), dim3(32, 8), 0, stream>>>(W2, W2T);
  // Phase A: Xc1 = x @ W1x + b1  (bf16 out); A2 unused (K2=0)
  gemm_kernel<<<dim3(256, 4), 256, 0, stream>>>(xb, xb, W1T, b1, Xc1b, 0, 0);
  // Phase B: recurrence; writes Hall[b][1..511] and final hidden (f32) to out tail
  elman_rec_kernel<<<64, 1024, 0, stream>>>(W1T, Xc1b, Hall, out + 16777216);
  // Phase C: out = x @ W2x + Hall @ W2h + b2  (f32 out)
  gemm_kernel<<<dim3(256, 4), 256, 0, stream>>>(xb, Hall, W2T, b2, out, 512, 1);
}